// Round 3
// baseline (571.516 us; speedup 1.0000x reference)
//
#include <hip/hip_runtime.h>

typedef __bf16 bf16x8 __attribute__((ext_vector_type(8)));
typedef float f32x4 __attribute__((ext_vector_type(4)));

static constexpr int TOKS = 43520;   // B * LQ
static constexpr int LQN  = 21760;

__device__ __forceinline__ unsigned short f2bf(float f) {
  union { float f; unsigned u; } v; v.f = f;
  return (unsigned short)((v.u + 0x7fffu + ((v.u >> 16) & 1u)) >> 16);
}
__device__ __forceinline__ float bf2f(unsigned short b) {
  union { unsigned u; float f; } v; v.u = ((unsigned)b) << 16; return v.f;
}

// async global->LDS DMA, 16B per lane; LDS dest = wave-uniform base + lane*16
__device__ __forceinline__ void gl2lds16(const unsigned short* g, unsigned short* l) {
  __builtin_amdgcn_global_load_lds(
      (const __attribute__((address_space(1))) unsigned*)g,
      (__attribute__((address_space(3))) unsigned*)l, 16, 0, 0);
}

// ---- all six weight transposes in one launch: Wt[n*K+k] = bf16(W[k*N+n])
__global__ __launch_bounds__(256) void wt6_kernel(
    const float* __restrict__ W_val, const float* __restrict__ W_off,
    const float* __restrict__ W_attn, const float* __restrict__ W_out,
    const float* __restrict__ W1, const float* __restrict__ W2,
    unsigned short* __restrict__ Wt_val, unsigned short* __restrict__ Wt_off,
    unsigned short* __restrict__ Wt_attn, unsigned short* __restrict__ Wt_out,
    unsigned short* __restrict__ Wt_1, unsigned short* __restrict__ Wt_2) {
  int gid = blockIdx.x * 256 + threadIdx.x;
  const float* W; unsigned short* Wt; int idx, K, nsh;
  if (gid < 65536)       { W = W_val;  Wt = Wt_val;  idx = gid;          K = 256;  nsh = 8;  }
  else if (gid < 131072) { W = W_off;  Wt = Wt_off;  idx = gid - 65536;  K = 256;  nsh = 8;  }
  else if (gid < 163840) { W = W_attn; Wt = Wt_attn; idx = gid - 131072; K = 256;  nsh = 7;  }
  else if (gid < 229376) { W = W_out;  Wt = Wt_out;  idx = gid - 163840; K = 256;  nsh = 8;  }
  else if (gid < 491520) { W = W1;     Wt = Wt_1;    idx = gid - 229376; K = 256;  nsh = 10; }
  else                   { W = W2;     Wt = Wt_2;    idx = gid - 491520; K = 1024; nsh = 8;  }
  int k = idx >> nsh, n = idx & ((1 << nsh) - 1);
  Wt[n * K + k] = f2bf(W[idx]);
}

// ---- prep: srcb = bf16(src); qb = bf16(src+pos)
__global__ __launch_bounds__(256) void prep_kernel(const float4* __restrict__ src,
                                                   const float4* __restrict__ pos,
                                                   ushort4* __restrict__ srcb,
                                                   ushort4* __restrict__ qb) {
  int i = blockIdx.x * 256 + threadIdx.x;
  float4 s = src[i], p = pos[i];
  srcb[i] = make_ushort4(f2bf(s.x), f2bf(s.y), f2bf(s.z), f2bf(s.w));
  qb[i]   = make_ushort4(f2bf(s.x + p.x), f2bf(s.y + p.y), f2bf(s.z + p.z), f2bf(s.w + p.w));
}

// ---- GEMM: C[M,N] = A[M,K] @ Bt[N,K]^T + bias
// m97-style: global_load_lds width-16 staging into UNPADDED [128][32] LDS tiles.
// outop: 0 = f32 store, 1 = bf16 store, 2 = relu -> bf16 store
__global__ __launch_bounds__(256) void gemm_bt(const unsigned short* __restrict__ A,
                                               const unsigned short* __restrict__ Bt,
                                               const float* __restrict__ bias,
                                               void* __restrict__ Cp,
                                               int N, int K, int outop) {
  __shared__ unsigned short As[128 * 32];   // unpadded: rows are 64 B, lane scatter lands exactly
  __shared__ unsigned short Bs[128 * 32];
  const int t = threadIdx.x;
  const int bm = blockIdx.x, bn = blockIdx.y;
  const int wave = t >> 6, lane = t & 63;
  const int wm = (wave & 1) << 6, wn = (wave >> 1) << 6;
  const int lr = lane & 15, lq = lane >> 4;
  // staging: wave stages rows [wave*32, wave*32+32) in 2 rounds of 16 rows;
  // lane i: row_in_round = i/4, col chunk = (i%4)*8 elems (16 B)
  const int srow = (wave << 5) + (lane >> 2);
  const int scol = (lane & 3) << 3;
  unsigned short* AsW = &As[(wave << 5) * 32];   // wave-uniform LDS base
  unsigned short* BsW = &Bs[(wave << 5) * 32];
  f32x4 acc[4][4] = {};

  const size_t abase = (size_t)bm * 128 * K;
  const size_t bbase = (size_t)bn * 128 * K;
  for (int k0 = 0; k0 < K; k0 += 32) {
    __syncthreads();
    const unsigned short* ga = A  + abase + (size_t)srow * K + k0 + scol;
    const unsigned short* gb = Bt + bbase + (size_t)srow * K + k0 + scol;
    gl2lds16(ga, AsW);
    gl2lds16(ga + (size_t)16 * K, AsW + 16 * 32);
    gl2lds16(gb, BsW);
    gl2lds16(gb + (size_t)16 * K, BsW + 16 * 32);
    __syncthreads();
    bf16x8 af[4], bfr[4];
#pragma unroll
    for (int i = 0; i < 4; i++) af[i] = *(const bf16x8*)&As[(wm + i * 16 + lr) * 32 + lq * 8];
#pragma unroll
    for (int j = 0; j < 4; j++) bfr[j] = *(const bf16x8*)&Bs[(wn + j * 16 + lr) * 32 + lq * 8];
#pragma unroll
    for (int i = 0; i < 4; i++)
#pragma unroll
      for (int j = 0; j < 4; j++)
        acc[i][j] = __builtin_amdgcn_mfma_f32_16x16x32_bf16(af[i], bfr[j], acc[i][j], 0, 0, 0);
  }
  // C/D mapping (m89/m91): col = lane&15, row = (lane>>4)*4 + reg
  const int rb = bm * 128 + wm + lq * 4;
  const int cbase = bn * 128 + wn + lr;
#pragma unroll
  for (int j = 0; j < 4; j++) {
    const int col = cbase + j * 16;
    const float bv = bias[col];
#pragma unroll
    for (int i = 0; i < 4; i++) {
#pragma unroll
      for (int r = 0; r < 4; r++) {
        float v = acc[i][j][r] + bv;
        size_t o = (size_t)(rb + i * 16 + r) * N + col;
        if (outop == 0) ((float*)Cp)[o] = v;
        else if (outop == 1) ((unsigned short*)Cp)[o] = f2bf(v);
        else ((unsigned short*)Cp)[o] = f2bf(fmaxf(v, 0.f));
      }
    }
  }
}

// ---- bf16x8 (uint4) fused unpack+FMA into fp32 acc
__device__ __forceinline__ void fma8(uint4 v, float w, float* a) {
  const unsigned uu[4] = {v.x, v.y, v.z, v.w};
#pragma unroll
  for (int i = 0; i < 4; i++) {
    union { unsigned u; float f; } lo, hi;
    lo.u = uu[i] << 16;
    hi.u = uu[i] & 0xffff0000u;
    a[2 * i]     += w * lo.f;
    a[2 * i + 1] += w * hi.f;
  }
}

// ---- deformable attention, two-phase:
// phase 1: 64 threads, one per (token,head): softmax + sample positions -> LDS
// phase 2: 256 threads = 8 tok x 8 head x 4 dim-chunks(8 dims, 16B loads)
__global__ __launch_bounds__(256) void deform_kernel(const unsigned short* __restrict__ valb,
                                                     const unsigned short* __restrict__ offb,
                                                     const unsigned short* __restrict__ logitb,
                                                     const float* __restrict__ refp,
                                                     unsigned short* __restrict__ outb) {
  __shared__ float4 sP[8][8][17];   // (x, y, attn_weight, pad); [17] spreads LDS banks
  const int t = threadIdx.x;
  const int tok0 = blockIdx.x * 8;
  const int SD[4] = {128, 64, 32, 16};

  if (t < 64) {
    const int g = t >> 3, h = t & 7;
    const int tok = tok0 + g;
    const unsigned short* lg = logitb + (size_t)tok * 128 + h * 16;
    uint4 lv0 = ((const uint4*)lg)[0];
    uint4 lv1 = ((const uint4*)lg)[1];
    const unsigned lw[8] = {lv0.x, lv0.y, lv0.z, lv0.w, lv1.x, lv1.y, lv1.z, lv1.w};
    float w[16];
#pragma unroll
    for (int i = 0; i < 8; i++) {
      union { unsigned u; float f; } lo, hi;
      lo.u = lw[i] << 16; hi.u = lw[i] & 0xffff0000u;
      w[2 * i] = lo.f; w[2 * i + 1] = hi.f;
    }
    float mx = -1e30f;
#pragma unroll
    for (int i = 0; i < 16; i++) mx = fmaxf(mx, w[i]);
    float s = 0.f;
#pragma unroll
    for (int i = 0; i < 16; i++) { w[i] = __expf(w[i] - mx); s += w[i]; }
    const float inv = 1.f / s;
    const unsigned short* of = offb + (size_t)tok * 256 + h * 32;
    uint4 o0 = ((const uint4*)of)[0], o1 = ((const uint4*)of)[1];
    uint4 o2 = ((const uint4*)of)[2], o3 = ((const uint4*)of)[3];
    const unsigned ow[16] = {o0.x, o0.y, o0.z, o0.w, o1.x, o1.y, o1.z, o1.w,
                             o2.x, o2.y, o2.z, o2.w, o3.x, o3.y, o3.z, o3.w};
    float off[32];
#pragma unroll
    for (int i = 0; i < 16; i++) {
      union { unsigned u; float f; } lo, hi;
      lo.u = ow[i] << 16; hi.u = ow[i] & 0xffff0000u;
      off[2 * i] = lo.f; off[2 * i + 1] = hi.f;
    }
    const float* rp = refp + (size_t)tok * 8;
#pragma unroll
    for (int l = 0; l < 4; l++) {
      const float Sf = (float)SD[l];
      const float rx = rp[l * 2 + 0] * Sf - 0.5f;
      const float ry = rp[l * 2 + 1] * Sf - 0.5f;
#pragma unroll
      for (int p = 0; p < 4; p++) {
        const int idx = l * 4 + p;
        sP[g][h][idx] = make_float4(rx + off[l * 8 + p * 2 + 0],
                                    ry + off[l * 8 + p * 2 + 1],
                                    w[idx] * inv, 0.f);
      }
    }
  }
  __syncthreads();

  const int g = t >> 5, h = (t >> 2) & 7, dc = t & 3;
  const int tok = tok0 + g;
  const int b = tok / LQN;
  float acc[8] = {0.f, 0.f, 0.f, 0.f, 0.f, 0.f, 0.f, 0.f};
  const int ST[4] = {0, 16384, 20480, 21504};
#pragma unroll
  for (int l = 0; l < 4; l++) {
    const int S = SD[l];
    const unsigned short* vb = valb + ((size_t)(b * LQN + ST[l])) * 256 + h * 32 + dc * 8;
#pragma unroll
    for (int p = 0; p < 4; p++) {
      float4 P = sP[g][h][l * 4 + p];
      const float x = P.x, y = P.y, aw = P.z;
      const float x0f = floorf(x), y0f = floorf(y);
      const int x0 = (int)x0f, y0 = (int)y0f;
      const float fx = x - x0f, fy = y - y0f;
      const bool xin0 = (x0 >= 0) & (x0 < S), xin1 = (x0 + 1 >= 0) & (x0 + 1 < S);
      const bool yin0 = (y0 >= 0) & (y0 < S), yin1 = (y0 + 1 >= 0) & (y0 + 1 < S);
      const float w00 = aw * (1.f - fx) * (1.f - fy) * (float)(xin0 & yin0);
      const float w10 = aw * fx * (1.f - fy)         * (float)(xin1 & yin0);
      const float w01 = aw * (1.f - fx) * fy         * (float)(xin0 & yin1);
      const float w11 = aw * fx * fy                 * (float)(xin1 & yin1);
      const int xc0 = min(max(x0, 0), S - 1), xc1 = min(max(x0 + 1, 0), S - 1);
      const int yc0 = min(max(y0, 0), S - 1), yc1 = min(max(y0 + 1, 0), S - 1);
      const unsigned short* r0 = vb + (size_t)(yc0 * S) * 256;
      const unsigned short* r1 = vb + (size_t)(yc1 * S) * 256;
      uint4 v00 = *(const uint4*)(r0 + (size_t)xc0 * 256);
      uint4 v10 = *(const uint4*)(r0 + (size_t)xc1 * 256);
      uint4 v01 = *(const uint4*)(r1 + (size_t)xc0 * 256);
      uint4 v11 = *(const uint4*)(r1 + (size_t)xc1 * 256);
      fma8(v00, w00, acc);
      fma8(v10, w10, acc);
      fma8(v01, w01, acc);
      fma8(v11, w11, acc);
    }
  }
  unsigned o[4];
#pragma unroll
  for (int i = 0; i < 4; i++)
    o[i] = (unsigned)f2bf(acc[2 * i]) | ((unsigned)f2bf(acc[2 * i + 1]) << 16);
  *(uint4*)(outb + (size_t)tok * 256 + h * 32 + dc * 8) = make_uint4(o[0], o[1], o[2], o[3]);
}

// ---- fused residual + layernorm; one wave per token row (64 lanes x float4)
__global__ __launch_bounds__(256) void ln_kernel(const float4* __restrict__ xa,
                                                 const float4* __restrict__ xb,
                                                 const float* __restrict__ g,
                                                 const float* __restrict__ beta,
                                                 float4* __restrict__ out,
                                                 ushort4* __restrict__ outb) {
  const int wv = blockIdx.x * 4 + (threadIdx.x >> 6);
  const int lane = threadIdx.x & 63;
  const size_t idx = (size_t)wv * 64 + lane;
  float4 a = xa[idx], c = xb[idx];
  float x0 = a.x + c.x, x1 = a.y + c.y, x2 = a.z + c.z, x3 = a.w + c.w;
  float sum = x0 + x1 + x2 + x3;
#pragma unroll
  for (int o = 32; o >= 1; o >>= 1) sum += __shfl_xor(sum, o, 64);
  const float mu = sum * (1.f / 256.f);
  float d0 = x0 - mu, d1 = x1 - mu, d2 = x2 - mu, d3 = x3 - mu;
  float ss = d0 * d0 + d1 * d1 + d2 * d2 + d3 * d3;
#pragma unroll
  for (int o = 32; o >= 1; o >>= 1) ss += __shfl_xor(ss, o, 64);
  const float rs = rsqrtf(ss * (1.f / 256.f) + 1e-5f);
  float4 gg = ((const float4*)g)[lane], bb = ((const float4*)beta)[lane];
  float4 y;
  y.x = d0 * rs * gg.x + bb.x;
  y.y = d1 * rs * gg.y + bb.y;
  y.z = d2 * rs * gg.z + bb.z;
  y.w = d3 * rs * gg.w + bb.w;
  out[idx] = y;
  if (outb) outb[idx] = make_ushort4(f2bf(y.x), f2bf(y.y), f2bf(y.z), f2bf(y.w));
}

extern "C" void kernel_launch(void* const* d_in, const int* in_sizes, int n_in,
                              void* d_out, int out_size, void* d_ws, size_t ws_size,
                              hipStream_t stream) {
  (void)in_sizes; (void)n_in; (void)out_size; (void)ws_size;
  const float* src    = (const float*)d_in[0];
  const float* pos    = (const float*)d_in[1];
  const float* refp   = (const float*)d_in[2];
  const float* W_off  = (const float*)d_in[3];
  const float* b_off  = (const float*)d_in[4];
  const float* W_attn = (const float*)d_in[5];
  const float* b_attn = (const float*)d_in[6];
  const float* W_val  = (const float*)d_in[7];
  const float* b_val  = (const float*)d_in[8];
  const float* W_out  = (const float*)d_in[9];
  const float* b_out  = (const float*)d_in[10];
  const float* ln1_g  = (const float*)d_in[11];
  const float* ln1_b  = (const float*)d_in[12];
  const float* W1     = (const float*)d_in[13];
  const float* b1     = (const float*)d_in[14];
  const float* W2     = (const float*)d_in[15];
  const float* b2     = (const float*)d_in[16];
  const float* ln2_g  = (const float*)d_in[17];
  const float* ln2_b  = (const float*)d_in[18];

  char* ws = (char*)d_ws;
  unsigned short* Wt_val  = (unsigned short*)ws;
  unsigned short* Wt_off  = Wt_val + 65536;
  unsigned short* Wt_attn = Wt_off + 65536;
  unsigned short* Wt_out  = Wt_attn + 32768;
  unsigned short* Wt_1    = Wt_out + 65536;
  unsigned short* Wt_2    = Wt_1 + 262144;
  const size_t WPOOL = 2u * 1024 * 1024;

  const size_t SZ_bf  = (size_t)TOKS * 256 * 2;
  const size_t SZ_bfh = (size_t)TOKS * 128 * 2;
  const size_t SZ_f   = (size_t)TOKS * 256 * 4;

  unsigned short* srcb   = (unsigned short*)(ws + WPOOL);
  unsigned short* qb     = (unsigned short*)(ws + WPOOL + SZ_bf);
  unsigned short* valb   = (unsigned short*)(ws + WPOOL + 2 * SZ_bf);
  unsigned short* offb   = (unsigned short*)(ws + WPOOL + 3 * SZ_bf);
  unsigned short* logitb = (unsigned short*)(ws + WPOOL + 4 * SZ_bf);
  float*          h_f    = (float*)(ws + WPOOL + 4 * SZ_bf + SZ_bfh);
  unsigned short* hb     = (unsigned short*)(ws + WPOOL + 4 * SZ_bf + SZ_bfh + SZ_f);
  // aliases (lifetime-disjoint):
  unsigned short* attnoutb = srcb;
  float*          C3       = (float*)qb;
  float*          C5       = (float*)qb;
  unsigned short* h_bf     = offb;

  // 1. all weight transposes in one launch
  wt6_kernel<<<2944, 256, 0, stream>>>(W_val, W_off, W_attn, W_out, W1, W2,
                                       Wt_val, Wt_off, Wt_attn, Wt_out, Wt_1, Wt_2);

  // 2. prep: src->bf16, query = src+pos -> bf16
  prep_kernel<<<10880, 256, 0, stream>>>((const float4*)src, (const float4*)pos,
                                         (ushort4*)srcb, (ushort4*)qb);

  // 3. projections
  gemm_bt<<<dim3(340, 2), 256, 0, stream>>>(srcb, Wt_val, b_val, valb, 256, 256, 1);
  gemm_bt<<<dim3(340, 2), 256, 0, stream>>>(qb, Wt_off, b_off, offb, 256, 256, 1);
  gemm_bt<<<dim3(340, 1), 256, 0, stream>>>(qb, Wt_attn, b_attn, logitb, 128, 256, 1);

  // 4. deformable attention gather (8 tokens per block)
  deform_kernel<<<TOKS / 8, 256, 0, stream>>>(valb, offb, logitb, refp, attnoutb);

  // 5. output projection + residual + LN1
  gemm_bt<<<dim3(340, 2), 256, 0, stream>>>(attnoutb, Wt_out, b_out, C3, 256, 256, 0);
  ln_kernel<<<10880, 256, 0, stream>>>((const float4*)src, (const float4*)C3,
                                       ln1_g, ln1_b, (float4*)h_f, (ushort4*)h_bf);

  // 6. FFN
  gemm_bt<<<dim3(340, 8), 256, 0, stream>>>(h_bf, Wt_1, b1, hb, 1024, 256, 2);
  gemm_bt<<<dim3(340, 2), 256, 0, stream>>>(hb, Wt_2, b2, C5, 256, 1024, 0);

  // 7. residual + LN2 -> out
  ln_kernel<<<10880, 256, 0, stream>>>((const float4*)h_f, (const float4*)C5,
                                       ln2_g, ln2_b, (float4*)d_out, (ushort4*)nullptr);
}

// Round 4
// 527.485 us; speedup vs baseline: 1.0835x; 1.0835x over previous
//
#include <hip/hip_runtime.h>

typedef __bf16 bf16x8 __attribute__((ext_vector_type(8)));
typedef float f32x4 __attribute__((ext_vector_type(4)));

static constexpr int TOKS = 43520;   // B * LQ
static constexpr int LQN  = 21760;

__device__ __forceinline__ unsigned short f2bf(float f) {
  union { float f; unsigned u; } v; v.f = f;
  return (unsigned short)((v.u + 0x7fffu + ((v.u >> 16) & 1u)) >> 16);
}
__device__ __forceinline__ float bf2f(unsigned short b) {
  union { unsigned u; float f; } v; v.u = ((unsigned)b) << 16; return v.f;
}

// ---- all weight transposes + bias concat in one launch
__global__ __launch_bounds__(256) void wt6_kernel(
    const float* __restrict__ W_val, const float* __restrict__ W_off,
    const float* __restrict__ W_attn, const float* __restrict__ W_out,
    const float* __restrict__ W1, const float* __restrict__ W2,
    const float* __restrict__ b_off, const float* __restrict__ b_attn,
    unsigned short* __restrict__ Wt_val, unsigned short* __restrict__ Wt_oa,
    unsigned short* __restrict__ Wt_out,
    unsigned short* __restrict__ Wt_1, unsigned short* __restrict__ Wt_2,
    float* __restrict__ b_oa) {
  int gid = blockIdx.x * 256 + threadIdx.x;
  if (gid >= 754048) return;
  if (gid >= 753664) {           // bias concat: b_oa = [b_off | b_attn]
    int i = gid - 753664;
    b_oa[i] = (i < 256) ? b_off[i] : b_attn[i - 256];
    return;
  }
  const float* W; unsigned short* Wt; int idx, K, nsh;
  if (gid < 65536)       { W = W_val;  Wt = Wt_val;          idx = gid;          K = 256;  nsh = 8;  }
  else if (gid < 131072) { W = W_off;  Wt = Wt_oa;           idx = gid - 65536;  K = 256;  nsh = 8;  }
  else if (gid < 163840) { W = W_attn; Wt = Wt_oa + 65536;   idx = gid - 131072; K = 256;  nsh = 7;  }
  else if (gid < 229376) { W = W_out;  Wt = Wt_out;          idx = gid - 163840; K = 256;  nsh = 8;  }
  else if (gid < 491520) { W = W1;     Wt = Wt_1;            idx = gid - 229376; K = 256;  nsh = 10; }
  else                   { W = W2;     Wt = Wt_2;            idx = gid - 491520; K = 1024; nsh = 8;  }
  int k = idx >> nsh, n = idx & ((1 << nsh) - 1);
  Wt[n * K + k] = f2bf(W[idx]);
}

// ---- prep: srcb = bf16(src); qb = bf16(src+pos)
__global__ __launch_bounds__(256) void prep_kernel(const float4* __restrict__ src,
                                                   const float4* __restrict__ pos,
                                                   ushort4* __restrict__ srcb,
                                                   ushort4* __restrict__ qb) {
  int i = blockIdx.x * 256 + threadIdx.x;
  float4 s = src[i], p = pos[i];
  srcb[i] = make_ushort4(f2bf(s.x), f2bf(s.y), f2bf(s.z), f2bf(s.w));
  qb[i]   = make_ushort4(f2bf(s.x + p.x), f2bf(s.y + p.y), f2bf(s.z + p.z), f2bf(s.w + p.w));
}

// ---- GEMM: C[M,N] = A[M,K] @ Bt[N,K]^T + bias  (R1 manual staging — proven)
// outop: 0 = f32 store, 1 = bf16 store, 2 = relu->bf16, 3 = +bf16 residual -> bf16
__global__ __launch_bounds__(256) void gemm_bt(const unsigned short* __restrict__ A,
                                               const unsigned short* __restrict__ Bt,
                                               const float* __restrict__ bias,
                                               const unsigned short* __restrict__ res,
                                               void* __restrict__ Cp,
                                               int N, int K, int outop) {
  __shared__ unsigned short As[128][40];
  __shared__ unsigned short Bs[128][40];
  const int t = threadIdx.x;
  const int bm = blockIdx.x, bn = blockIdx.y;
  const int wave = t >> 6, lane = t & 63;
  const int wm = (wave & 1) << 6, wn = (wave >> 1) << 6;
  const int lr = lane & 15, lq = lane >> 4;
  const int row0 = t >> 2, cb0 = (t & 3) * 8;
  const int row1 = row0 + 64;
  f32x4 acc[4][4] = {};

  const size_t abase = (size_t)bm * 128 * K;
  const size_t bbase = (size_t)bn * 128 * K;
  for (int k0 = 0; k0 < K; k0 += 32) {
    __syncthreads();
    *(uint4*)&As[row0][cb0] = *(const uint4*)&A[abase + (size_t)row0 * K + k0 + cb0];
    *(uint4*)&As[row1][cb0] = *(const uint4*)&A[abase + (size_t)row1 * K + k0 + cb0];
    *(uint4*)&Bs[row0][cb0] = *(const uint4*)&Bt[bbase + (size_t)row0 * K + k0 + cb0];
    *(uint4*)&Bs[row1][cb0] = *(const uint4*)&Bt[bbase + (size_t)row1 * K + k0 + cb0];
    __syncthreads();
    bf16x8 af[4], bfr[4];
#pragma unroll
    for (int i = 0; i < 4; i++) af[i] = *(const bf16x8*)&As[wm + i * 16 + lr][lq * 8];
#pragma unroll
    for (int j = 0; j < 4; j++) bfr[j] = *(const bf16x8*)&Bs[wn + j * 16 + lr][lq * 8];
#pragma unroll
    for (int i = 0; i < 4; i++)
#pragma unroll
      for (int j = 0; j < 4; j++)
        acc[i][j] = __builtin_amdgcn_mfma_f32_16x16x32_bf16(af[i], bfr[j], acc[i][j], 0, 0, 0);
  }
  const int rb = bm * 128 + wm + lq * 4;
  const int cbase = bn * 128 + wn + lr;
#pragma unroll
  for (int j = 0; j < 4; j++) {
    const int col = cbase + j * 16;
    const float bv = bias[col];
#pragma unroll
    for (int i = 0; i < 4; i++) {
#pragma unroll
      for (int r = 0; r < 4; r++) {
        float v = acc[i][j][r] + bv;
        size_t o = (size_t)(rb + i * 16 + r) * N + col;
        if (outop == 0) ((float*)Cp)[o] = v;
        else if (outop == 1) ((unsigned short*)Cp)[o] = f2bf(v);
        else if (outop == 2) ((unsigned short*)Cp)[o] = f2bf(fmaxf(v, 0.f));
        else ((unsigned short*)Cp)[o] = f2bf(v + bf2f(res[o]));
      }
    }
  }
}

// ---- bf16x8 (uint4) fused unpack+FMA into fp32 acc
__device__ __forceinline__ void fma8(uint4 v, float w, float* a) {
  const unsigned uu[4] = {v.x, v.y, v.z, v.w};
#pragma unroll
  for (int i = 0; i < 4; i++) {
    union { unsigned u; float f; } lo, hi;
    lo.u = uu[i] << 16;
    hi.u = uu[i] & 0xffff0000u;
    a[2 * i]     += w * lo.f;
    a[2 * i + 1] += w * hi.f;
  }
}

// ---- deformable attention, two-phase with precomputed bilinear tables.
// oab layout per token: [0..255] offsets (8h x 32), [256..383] logits (8h x 16), stride 384.
// Block swizzle: contiguous token ranges per XCD for L2 locality.
__global__ __launch_bounds__(256) void deform_kernel(const unsigned short* __restrict__ valb,
                                                     const unsigned short* __restrict__ oab,
                                                     const float* __restrict__ refp,
                                                     unsigned short* __restrict__ outb) {
  __shared__ float4 sW[8][8][17];   // per (tok,head,point): 4 corner weights (x attn)
  __shared__ int4   sI[8][8][17];   // per (tok,head,point): 4 clamped element indices
  const int t = threadIdx.x;
  // XCD swizzle: blockIdx round-robins across 8 XCDs; give each XCD a contiguous slice.
  const int bid = blockIdx.x;                     // 5440 blocks
  const int nb = (bid & 7) * 680 + (bid >> 3);
  const int tok0 = nb * 8;
  const int SD[4] = {128, 64, 32, 16};

  if (t < 64) {
    const int g = t >> 3, h = t & 7;
    const int tok = tok0 + g;
    const unsigned short* lg = oab + (size_t)tok * 384 + 256 + h * 16;
    uint4 lv0 = ((const uint4*)lg)[0];
    uint4 lv1 = ((const uint4*)lg)[1];
    const unsigned lw[8] = {lv0.x, lv0.y, lv0.z, lv0.w, lv1.x, lv1.y, lv1.z, lv1.w};
    float w[16];
#pragma unroll
    for (int i = 0; i < 8; i++) {
      union { unsigned u; float f; } lo, hi;
      lo.u = lw[i] << 16; hi.u = lw[i] & 0xffff0000u;
      w[2 * i] = lo.f; w[2 * i + 1] = hi.f;
    }
    float mx = -1e30f;
#pragma unroll
    for (int i = 0; i < 16; i++) mx = fmaxf(mx, w[i]);
    float s = 0.f;
#pragma unroll
    for (int i = 0; i < 16; i++) { w[i] = __expf(w[i] - mx); s += w[i]; }
    const float inv = 1.f / s;
    const unsigned short* of = oab + (size_t)tok * 384 + h * 32;
    uint4 o0 = ((const uint4*)of)[0], o1 = ((const uint4*)of)[1];
    uint4 o2 = ((const uint4*)of)[2], o3 = ((const uint4*)of)[3];
    const unsigned ow[16] = {o0.x, o0.y, o0.z, o0.w, o1.x, o1.y, o1.z, o1.w,
                             o2.x, o2.y, o2.z, o2.w, o3.x, o3.y, o3.z, o3.w};
    float off[32];
#pragma unroll
    for (int i = 0; i < 16; i++) {
      union { unsigned u; float f; } lo, hi;
      lo.u = ow[i] << 16; hi.u = ow[i] & 0xffff0000u;
      off[2 * i] = lo.f; off[2 * i + 1] = hi.f;
    }
    const float* rp = refp + (size_t)tok * 8;
#pragma unroll
    for (int l = 0; l < 4; l++) {
      const int S = SD[l];
      const float Sf = (float)S;
      const float rx = rp[l * 2 + 0] * Sf - 0.5f;
      const float ry = rp[l * 2 + 1] * Sf - 0.5f;
#pragma unroll
      for (int p = 0; p < 4; p++) {
        const int idx = l * 4 + p;
        const float x = rx + off[l * 8 + p * 2 + 0];
        const float y = ry + off[l * 8 + p * 2 + 1];
        const float aw = w[idx] * inv;
        const float x0f = floorf(x), y0f = floorf(y);
        const int x0 = (int)x0f, y0 = (int)y0f;
        const float fx = x - x0f, fy = y - y0f;
        const bool xin0 = (x0 >= 0) & (x0 < S), xin1 = (x0 + 1 >= 0) & (x0 + 1 < S);
        const bool yin0 = (y0 >= 0) & (y0 < S), yin1 = (y0 + 1 >= 0) & (y0 + 1 < S);
        const int xc0 = min(max(x0, 0), S - 1), xc1 = min(max(x0 + 1, 0), S - 1);
        const int yc0 = min(max(y0, 0), S - 1), yc1 = min(max(y0 + 1, 0), S - 1);
        sW[g][h][idx] = make_float4(aw * (1.f - fx) * (1.f - fy) * (float)(xin0 & yin0),
                                    aw * fx * (1.f - fy)         * (float)(xin1 & yin0),
                                    aw * (1.f - fx) * fy         * (float)(xin0 & yin1),
                                    aw * fx * fy                 * (float)(xin1 & yin1));
        sI[g][h][idx] = make_int4(yc0 * S + xc0, yc0 * S + xc1,
                                  yc1 * S + xc0, yc1 * S + xc1);
      }
    }
  }
  __syncthreads();

  const int g = t >> 5, h = (t >> 2) & 7, dc = t & 3;
  const int tok = tok0 + g;
  const int b = tok / LQN;
  float acc[8] = {0.f, 0.f, 0.f, 0.f, 0.f, 0.f, 0.f, 0.f};
  const int ST[4] = {0, 16384, 20480, 21504};
#pragma unroll
  for (int l = 0; l < 4; l++) {
    const unsigned short* vb = valb + ((size_t)(b * LQN + ST[l])) * 256 + h * 32 + dc * 8;
#pragma unroll
    for (int p = 0; p < 4; p++) {
      float4 W4 = sW[g][h][l * 4 + p];
      int4   I4 = sI[g][h][l * 4 + p];
      uint4 v00 = *(const uint4*)(vb + (size_t)I4.x * 256);
      uint4 v10 = *(const uint4*)(vb + (size_t)I4.y * 256);
      uint4 v01 = *(const uint4*)(vb + (size_t)I4.z * 256);
      uint4 v11 = *(const uint4*)(vb + (size_t)I4.w * 256);
      fma8(v00, W4.x, acc);
      fma8(v10, W4.y, acc);
      fma8(v01, W4.z, acc);
      fma8(v11, W4.w, acc);
    }
  }
  unsigned o[4];
#pragma unroll
  for (int i = 0; i < 4; i++)
    o[i] = (unsigned)f2bf(acc[2 * i]) | ((unsigned)f2bf(acc[2 * i + 1]) << 16);
  *(uint4*)(outb + (size_t)tok * 256 + h * 32 + dc * 8) = make_uint4(o[0], o[1], o[2], o[3]);
}

// ---- layernorm on bf16 pre-LN input; one wave per token (64 lanes x 4 elems)
// OUT_F32=0 -> bf16 out, 1 -> f32 out
template <int OUT_F32>
__global__ __launch_bounds__(256) void ln_kernel(const ushort4* __restrict__ in,
                                                 const float* __restrict__ g,
                                                 const float* __restrict__ beta,
                                                 void* __restrict__ outp) {
  const int wv = blockIdx.x * 4 + (threadIdx.x >> 6);
  const int lane = threadIdx.x & 63;
  const size_t idx = (size_t)wv * 64 + lane;
  ushort4 u = in[idx];
  float x0 = bf2f(u.x), x1 = bf2f(u.y), x2 = bf2f(u.z), x3 = bf2f(u.w);
  float sum = x0 + x1 + x2 + x3;
#pragma unroll
  for (int o = 32; o >= 1; o >>= 1) sum += __shfl_xor(sum, o, 64);
  const float mu = sum * (1.f / 256.f);
  float d0 = x0 - mu, d1 = x1 - mu, d2 = x2 - mu, d3 = x3 - mu;
  float ss = d0 * d0 + d1 * d1 + d2 * d2 + d3 * d3;
#pragma unroll
  for (int o = 32; o >= 1; o >>= 1) ss += __shfl_xor(ss, o, 64);
  const float rs = rsqrtf(ss * (1.f / 256.f) + 1e-5f);
  float4 gg = ((const float4*)g)[lane], bb = ((const float4*)beta)[lane];
  float y0 = d0 * rs * gg.x + bb.x;
  float y1 = d1 * rs * gg.y + bb.y;
  float y2 = d2 * rs * gg.z + bb.z;
  float y3 = d3 * rs * gg.w + bb.w;
  if (OUT_F32) ((float4*)outp)[idx] = make_float4(y0, y1, y2, y3);
  else ((ushort4*)outp)[idx] = make_ushort4(f2bf(y0), f2bf(y1), f2bf(y2), f2bf(y3));
}

extern "C" void kernel_launch(void* const* d_in, const int* in_sizes, int n_in,
                              void* d_out, int out_size, void* d_ws, size_t ws_size,
                              hipStream_t stream) {
  (void)in_sizes; (void)n_in; (void)out_size; (void)ws_size;
  const float* src    = (const float*)d_in[0];
  const float* pos    = (const float*)d_in[1];
  const float* refp   = (const float*)d_in[2];
  const float* W_off  = (const float*)d_in[3];
  const float* b_off  = (const float*)d_in[4];
  const float* W_attn = (const float*)d_in[5];
  const float* b_attn = (const float*)d_in[6];
  const float* W_val  = (const float*)d_in[7];
  const float* b_val  = (const float*)d_in[8];
  const float* W_out  = (const float*)d_in[9];
  const float* b_out  = (const float*)d_in[10];
  const float* ln1_g  = (const float*)d_in[11];
  const float* ln1_b  = (const float*)d_in[12];
  const float* W1     = (const float*)d_in[13];
  const float* b1     = (const float*)d_in[14];
  const float* W2     = (const float*)d_in[15];
  const float* b2     = (const float*)d_in[16];
  const float* ln2_g  = (const float*)d_in[17];
  const float* ln2_b  = (const float*)d_in[18];

  char* ws = (char*)d_ws;
  unsigned short* Wt_val = (unsigned short*)ws;          // 65536
  unsigned short* Wt_oa  = Wt_val + 65536;               // 98304 (off 256 rows + attn 128 rows)
  unsigned short* Wt_out = Wt_oa + 98304;                // 65536
  unsigned short* Wt_1   = Wt_out + 65536;               // 262144
  unsigned short* Wt_2   = Wt_1 + 262144;                // 262144
  float*          b_oa   = (float*)(Wt_2 + 262144);      // 384
  const size_t WPOOL = 2u * 1024 * 1024;

  const size_t SZ_bf = (size_t)TOKS * 256 * 2;           // 22.3 MB
  const size_t SZ_oa = (size_t)TOKS * 384 * 2;           // 33.4 MB

  unsigned short* srcb = (unsigned short*)(ws + WPOOL);              // live: prep..out-gemm(res)
  unsigned short* qb   = (unsigned short*)(ws + WPOOL + SZ_bf);      // live: prep..oa-gemm
  unsigned short* valb = (unsigned short*)(ws + WPOOL + 2 * SZ_bf);  // live: val-gemm..deform
  unsigned short* oab  = (unsigned short*)(ws + WPOOL + 3 * SZ_bf);  // live: oa-gemm..deform
  unsigned short* h_bf = (unsigned short*)(ws + WPOOL + 3 * SZ_bf + SZ_oa); // LN1..W2(res)
  unsigned short* hb   = (unsigned short*)(ws + WPOOL + 3 * SZ_bf + SZ_oa + SZ_bf); // W1..W2
  // aliases (lifetime-disjoint):
  unsigned short* attnoutb = qb;     // deform out; qb dead after oa-gemm
  unsigned short* preLN1b  = valb;   // out-gemm out; valb dead after deform
  unsigned short* preLN2b  = valb;   // W2 out; preLN1b dead after LN1

  // 1. weight transposes + bias concat (one launch)
  wt6_kernel<<<2946, 256, 0, stream>>>(W_val, W_off, W_attn, W_out, W1, W2, b_off, b_attn,
                                       Wt_val, Wt_oa, Wt_out, Wt_1, Wt_2, b_oa);

  // 2. prep
  prep_kernel<<<10880, 256, 0, stream>>>((const float4*)src, (const float4*)pos,
                                         (ushort4*)srcb, (ushort4*)qb);

  // 3. projections (off+attn merged, N=384)
  gemm_bt<<<dim3(340, 2), 256, 0, stream>>>(srcb, Wt_val, b_val, nullptr, valb, 256, 256, 1);
  gemm_bt<<<dim3(340, 3), 256, 0, stream>>>(qb, Wt_oa, b_oa, nullptr, oab, 384, 256, 1);

  // 4. deformable attention (8 tokens/block, XCD-swizzled)
  deform_kernel<<<TOKS / 8, 256, 0, stream>>>(valb, oab, refp, attnoutb);

  // 5. out-proj + residual(src) fused -> preLN1 (bf16); LN1 -> h_bf
  gemm_bt<<<dim3(340, 2), 256, 0, stream>>>(attnoutb, Wt_out, b_out, srcb, preLN1b, 256, 256, 3);
  ln_kernel<0><<<10880, 256, 0, stream>>>((const ushort4*)preLN1b, ln1_g, ln1_b, h_bf);

  // 6. FFN: W1+relu -> hb; W2 + residual(h) fused -> preLN2 (bf16)
  gemm_bt<<<dim3(340, 8), 256, 0, stream>>>(h_bf, Wt_1, b1, nullptr, hb, 1024, 256, 2);
  gemm_bt<<<dim3(340, 2), 256, 0, stream>>>(hb, Wt_2, b2, h_bf, preLN2b, 256, 1024, 3);

  // 7. LN2 -> d_out (f32)
  ln_kernel<1><<<10880, 256, 0, stream>>>((const ushort4*)preLN2b, ln2_g, ln2_b, d_out);
}

// Round 5
// 441.835 us; speedup vs baseline: 1.2935x; 1.1939x over previous
//
#include <hip/hip_runtime.h>

typedef __bf16 bf16x8 __attribute__((ext_vector_type(8)));
typedef float f32x4 __attribute__((ext_vector_type(4)));

static constexpr int TOKS = 43520;   // B * LQ
static constexpr int LQN  = 21760;

__device__ __forceinline__ unsigned short f2bf(float f) {
  union { float f; unsigned u; } v; v.f = f;
  return (unsigned short)((v.u + 0x7fffu + ((v.u >> 16) & 1u)) >> 16);
}
__device__ __forceinline__ float bf2f(unsigned short b) {
  union { unsigned u; float f; } v; v.u = ((unsigned)b) << 16; return v.f;
}

// ---- fused prep + weight transpose + bias concat (one launch)
// blocks [0,10880): prep; blocks [10880, 13826): wt/bias
__global__ __launch_bounds__(256) void prewt_kernel(
    const float* __restrict__ src, const float* __restrict__ pos,
    unsigned short* __restrict__ srcb, unsigned short* __restrict__ qb,
    const float* __restrict__ W_val, const float* __restrict__ W_off,
    const float* __restrict__ W_attn, const float* __restrict__ W_out,
    const float* __restrict__ W1, const float* __restrict__ W2,
    const float* __restrict__ b_off, const float* __restrict__ b_attn,
    unsigned short* __restrict__ Wt_val, unsigned short* __restrict__ Wt_oa,
    unsigned short* __restrict__ Wt_out,
    unsigned short* __restrict__ Wt_1, unsigned short* __restrict__ Wt_2,
    float* __restrict__ b_oa) {
  const int bid = blockIdx.x;
  if (bid < 10880) {
    int i = bid * 256 + threadIdx.x;
    float4 s = ((const float4*)src)[i], p = ((const float4*)pos)[i];
    ((ushort4*)srcb)[i] = make_ushort4(f2bf(s.x), f2bf(s.y), f2bf(s.z), f2bf(s.w));
    ((ushort4*)qb)[i]   = make_ushort4(f2bf(s.x + p.x), f2bf(s.y + p.y),
                                       f2bf(s.z + p.z), f2bf(s.w + p.w));
    return;
  }
  int gid = (bid - 10880) * 256 + threadIdx.x;
  if (gid >= 754048) return;
  if (gid >= 753664) {           // bias concat: b_oa = [b_off | b_attn]
    int i = gid - 753664;
    b_oa[i] = (i < 256) ? b_off[i] : b_attn[i - 256];
    return;
  }
  const float* W; unsigned short* Wt; int idx, K, nsh;
  if (gid < 65536)       { W = W_val;  Wt = Wt_val;          idx = gid;          K = 256;  nsh = 8;  }
  else if (gid < 131072) { W = W_off;  Wt = Wt_oa;           idx = gid - 65536;  K = 256;  nsh = 8;  }
  else if (gid < 163840) { W = W_attn; Wt = Wt_oa + 65536;   idx = gid - 131072; K = 256;  nsh = 7;  }
  else if (gid < 229376) { W = W_out;  Wt = Wt_out;          idx = gid - 163840; K = 256;  nsh = 8;  }
  else if (gid < 491520) { W = W1;     Wt = Wt_1;            idx = gid - 229376; K = 256;  nsh = 10; }
  else                   { W = W2;     Wt = Wt_2;            idx = gid - 491520; K = 1024; nsh = 8;  }
  int k = idx >> nsh, n = idx & ((1 << nsh) - 1);
  Wt[n * K + k] = f2bf(W[idx]);
}

// ---- GEMM body: C[M,N] = A[M,K] @ Bt[N,K]^T + bias, software-pipelined staging.
// OUTOP: 1 = bf16 store, 2 = relu->bf16, 3 = +bf16 residual -> bf16
template <int K, int OUTOP>
__device__ __forceinline__ void gemm_body(unsigned short* __restrict__ As,
                                          unsigned short* __restrict__ Bs,
                                          const unsigned short* __restrict__ A,
                                          const unsigned short* __restrict__ Bt,
                                          const float* __restrict__ bias,
                                          const unsigned short* __restrict__ res,
                                          unsigned short* __restrict__ Cp,
                                          int N, int bm, int bn) {
  const int t = threadIdx.x;
  const int wave = t >> 6, lane = t & 63;
  const int wm = (wave & 1) << 6, wn = (wave >> 1) << 6;
  const int lr = lane & 15, lq = lane >> 4;
  const int row0 = t >> 2, cb0 = (t & 3) << 3;
  f32x4 acc[4][4] = {};
  const unsigned short* ga = A  + (size_t)(bm * 128 + row0) * K + cb0;
  const unsigned short* gb = Bt + (size_t)(bn * 128 + row0) * K + cb0;
  const size_t gs = (size_t)64 * K;
  // prologue prefetch (k0 = 0)
  uint4 pa0 = *(const uint4*)ga;
  uint4 pa1 = *(const uint4*)(ga + gs);
  uint4 pb0 = *(const uint4*)gb;
  uint4 pb1 = *(const uint4*)(gb + gs);
#pragma unroll 1
  for (int k0 = 0; k0 < K; k0 += 32) {
    __syncthreads();
    *(uint4*)&As[row0 * 40 + cb0] = pa0;
    *(uint4*)&As[(row0 + 64) * 40 + cb0] = pa1;
    *(uint4*)&Bs[row0 * 40 + cb0] = pb0;
    *(uint4*)&Bs[(row0 + 64) * 40 + cb0] = pb1;
    __syncthreads();
    if (k0 + 32 < K) {           // issue next tile's loads; in flight during MFMA
      pa0 = *(const uint4*)(ga + k0 + 32);
      pa1 = *(const uint4*)(ga + gs + k0 + 32);
      pb0 = *(const uint4*)(gb + k0 + 32);
      pb1 = *(const uint4*)(gb + gs + k0 + 32);
    }
    bf16x8 af[4], bfr[4];
#pragma unroll
    for (int i = 0; i < 4; i++) af[i] = *(const bf16x8*)&As[(wm + i * 16 + lr) * 40 + lq * 8];
#pragma unroll
    for (int j = 0; j < 4; j++) bfr[j] = *(const bf16x8*)&Bs[(wn + j * 16 + lr) * 40 + lq * 8];
#pragma unroll
    for (int i = 0; i < 4; i++)
#pragma unroll
      for (int j = 0; j < 4; j++)
        acc[i][j] = __builtin_amdgcn_mfma_f32_16x16x32_bf16(af[i], bfr[j], acc[i][j], 0, 0, 0);
  }
  // C/D mapping (m89/m91): col = lane&15, row = (lane>>4)*4 + reg
  const int rb = bm * 128 + wm + lq * 4;
  const int cbase = bn * 128 + wn + lr;
#pragma unroll
  for (int j = 0; j < 4; j++) {
    const int col = cbase + j * 16;
    const float bv = bias[col];
#pragma unroll
    for (int i = 0; i < 4; i++) {
#pragma unroll
      for (int r = 0; r < 4; r++) {
        float v = acc[i][j][r] + bv;
        size_t o = (size_t)(rb + i * 16 + r) * N + col;
        if (OUTOP == 1) Cp[o] = f2bf(v);
        else if (OUTOP == 2) Cp[o] = f2bf(fmaxf(v, 0.f));
        else Cp[o] = f2bf(v + bf2f(res[o]));
      }
    }
  }
}

// merged value + offset/attn projections (both K=256, bf16 out)
__global__ __launch_bounds__(256) void proj_kernel(
    const unsigned short* __restrict__ srcb, const unsigned short* __restrict__ qb,
    const unsigned short* __restrict__ Wt_val, const unsigned short* __restrict__ Wt_oa,
    const float* __restrict__ b_val, const float* __restrict__ b_oa,
    unsigned short* __restrict__ valb, unsigned short* __restrict__ oab) {
  __shared__ unsigned short As[128 * 40];
  __shared__ unsigned short Bs[128 * 40];
  const int bn = blockIdx.y;
  if (bn < 2)
    gemm_body<256, 1>(As, Bs, srcb, Wt_val, b_val, nullptr, valb, 256, blockIdx.x, bn);
  else
    gemm_body<256, 1>(As, Bs, qb, Wt_oa, b_oa, nullptr, oab, 384, blockIdx.x, bn - 2);
}

// out-proj + residual
__global__ __launch_bounds__(256) void gemm_out_kernel(
    const unsigned short* __restrict__ A, const unsigned short* __restrict__ Bt,
    const float* __restrict__ bias, const unsigned short* __restrict__ res,
    unsigned short* __restrict__ C) {
  __shared__ unsigned short As[128 * 40];
  __shared__ unsigned short Bs[128 * 40];
  gemm_body<256, 3>(As, Bs, A, Bt, bias, res, C, 256, blockIdx.x, blockIdx.y);
}

// FFN1: relu epilogue, N=1024
__global__ __launch_bounds__(256) void gemm_ffn1_kernel(
    const unsigned short* __restrict__ A, const unsigned short* __restrict__ Bt,
    const float* __restrict__ bias, unsigned short* __restrict__ C) {
  __shared__ unsigned short As[128 * 40];
  __shared__ unsigned short Bs[128 * 40];
  gemm_body<256, 2>(As, Bs, A, Bt, bias, nullptr, C, 1024, blockIdx.x, blockIdx.y);
}

// FFN2: K=1024, residual
__global__ __launch_bounds__(256) void gemm_ffn2_kernel(
    const unsigned short* __restrict__ A, const unsigned short* __restrict__ Bt,
    const float* __restrict__ bias, const unsigned short* __restrict__ res,
    unsigned short* __restrict__ C) {
  __shared__ unsigned short As[128 * 40];
  __shared__ unsigned short Bs[128 * 40];
  gemm_body<1024, 3>(As, Bs, A, Bt, bias, res, C, 256, blockIdx.x, blockIdx.y);
}

// ---- bf16x8 (uint4) fused unpack+FMA into fp32 acc
__device__ __forceinline__ void fma8(uint4 v, float w, float* a) {
  const unsigned uu[4] = {v.x, v.y, v.z, v.w};
#pragma unroll
  for (int i = 0; i < 4; i++) {
    union { unsigned u; float f; } lo, hi;
    lo.u = uu[i] << 16;
    hi.u = uu[i] & 0xffff0000u;
    a[2 * i]     += w * lo.f;
    a[2 * i + 1] += w * hi.f;
  }
}

// ---- deformable attention, two-phase with precomputed bilinear tables.
// oab per token: [0..255] offsets (8h x 32), [256..383] logits (8h x 16), stride 384.
__global__ __launch_bounds__(256) void deform_kernel(const unsigned short* __restrict__ valb,
                                                     const unsigned short* __restrict__ oab,
                                                     const float* __restrict__ refp,
                                                     unsigned short* __restrict__ outb) {
  __shared__ float4  sW[8][8][17];   // 4 corner weights (x attn); [17] spreads banks
  __shared__ ushort4 sI[8][8][17];   // 4 clamped element indices (max 16383 fits u16)
  const int t = threadIdx.x;
  const int bid = blockIdx.x;                     // 5440 blocks
  const int nb = (bid & 7) * 680 + (bid >> 3);    // XCD-contiguous slices
  const int tok0 = nb * 8;
  const int SD[4] = {128, 64, 32, 16};

  if (t < 64) {
    const int g = t >> 3, h = t & 7;
    const int tok = tok0 + g;
    const unsigned short* lg = oab + (size_t)tok * 384 + 256 + h * 16;
    uint4 lv0 = ((const uint4*)lg)[0];
    uint4 lv1 = ((const uint4*)lg)[1];
    const unsigned lw[8] = {lv0.x, lv0.y, lv0.z, lv0.w, lv1.x, lv1.y, lv1.z, lv1.w};
    float w[16];
#pragma unroll
    for (int i = 0; i < 8; i++) {
      union { unsigned u; float f; } lo, hi;
      lo.u = lw[i] << 16; hi.u = lw[i] & 0xffff0000u;
      w[2 * i] = lo.f; w[2 * i + 1] = hi.f;
    }
    float mx = -1e30f;
#pragma unroll
    for (int i = 0; i < 16; i++) mx = fmaxf(mx, w[i]);
    float s = 0.f;
#pragma unroll
    for (int i = 0; i < 16; i++) { w[i] = __expf(w[i] - mx); s += w[i]; }
    const float inv = 1.f / s;
    const unsigned short* of = oab + (size_t)tok * 384 + h * 32;
    uint4 o0 = ((const uint4*)of)[0], o1 = ((const uint4*)of)[1];
    uint4 o2 = ((const uint4*)of)[2], o3 = ((const uint4*)of)[3];
    const unsigned ow[16] = {o0.x, o0.y, o0.z, o0.w, o1.x, o1.y, o1.z, o1.w,
                             o2.x, o2.y, o2.z, o2.w, o3.x, o3.y, o3.z, o3.w};
    float off[32];
#pragma unroll
    for (int i = 0; i < 16; i++) {
      union { unsigned u; float f; } lo, hi;
      lo.u = ow[i] << 16; hi.u = ow[i] & 0xffff0000u;
      off[2 * i] = lo.f; off[2 * i + 1] = hi.f;
    }
    const float* rp = refp + (size_t)tok * 8;
#pragma unroll
    for (int l = 0; l < 4; l++) {
      const int S = SD[l];
      const float Sf = (float)S;
      const float rx = rp[l * 2 + 0] * Sf - 0.5f;
      const float ry = rp[l * 2 + 1] * Sf - 0.5f;
#pragma unroll
      for (int p = 0; p < 4; p++) {
        const int idx = l * 4 + p;
        const float x = rx + off[l * 8 + p * 2 + 0];
        const float y = ry + off[l * 8 + p * 2 + 1];
        const float aw = w[idx] * inv;
        const float x0f = floorf(x), y0f = floorf(y);
        const int x0 = (int)x0f, y0 = (int)y0f;
        const float fx = x - x0f, fy = y - y0f;
        const bool xin0 = (x0 >= 0) & (x0 < S), xin1 = (x0 + 1 >= 0) & (x0 + 1 < S);
        const bool yin0 = (y0 >= 0) & (y0 < S), yin1 = (y0 + 1 >= 0) & (y0 + 1 < S);
        const int xc0 = min(max(x0, 0), S - 1), xc1 = min(max(x0 + 1, 0), S - 1);
        const int yc0 = min(max(y0, 0), S - 1), yc1 = min(max(y0 + 1, 0), S - 1);
        sW[g][h][idx] = make_float4(aw * (1.f - fx) * (1.f - fy) * (float)(xin0 & yin0),
                                    aw * fx * (1.f - fy)         * (float)(xin1 & yin0),
                                    aw * (1.f - fx) * fy         * (float)(xin0 & yin1),
                                    aw * fx * fy                 * (float)(xin1 & yin1));
        sI[g][h][idx] = make_ushort4((unsigned short)(yc0 * S + xc0),
                                     (unsigned short)(yc0 * S + xc1),
                                     (unsigned short)(yc1 * S + xc0),
                                     (unsigned short)(yc1 * S + xc1));
      }
    }
  }
  __syncthreads();

  const int g = t >> 5, h = (t >> 2) & 7, dc = t & 3;
  const int tok = tok0 + g;
  const int b = tok / LQN;
  float acc[8] = {0.f, 0.f, 0.f, 0.f, 0.f, 0.f, 0.f, 0.f};
  const int ST[4] = {0, 16384, 20480, 21504};
#pragma unroll
  for (int l = 0; l < 4; l++) {
    const unsigned short* vb = valb + ((size_t)(b * LQN + ST[l])) * 256 + h * 32 + dc * 8;
#pragma unroll
    for (int p = 0; p < 4; p++) {
      float4  W4 = sW[g][h][l * 4 + p];
      ushort4 I4 = sI[g][h][l * 4 + p];
      uint4 v00 = *(const uint4*)(vb + (size_t)I4.x * 256);
      uint4 v10 = *(const uint4*)(vb + (size_t)I4.y * 256);
      uint4 v01 = *(const uint4*)(vb + (size_t)I4.z * 256);
      uint4 v11 = *(const uint4*)(vb + (size_t)I4.w * 256);
      fma8(v00, W4.x, acc);
      fma8(v10, W4.y, acc);
      fma8(v01, W4.z, acc);
      fma8(v11, W4.w, acc);
    }
  }
  unsigned o[4];
#pragma unroll
  for (int i = 0; i < 4; i++)
    o[i] = (unsigned)f2bf(acc[2 * i]) | ((unsigned)f2bf(acc[2 * i + 1]) << 16);
  *(uint4*)(outb + (size_t)tok * 256 + h * 32 + dc * 8) = make_uint4(o[0], o[1], o[2], o[3]);
}

// ---- layernorm on bf16 pre-LN input; one wave per token (64 lanes x 4 elems)
template <int OUT_F32>
__global__ __launch_bounds__(256) void ln_kernel(const ushort4* __restrict__ in,
                                                 const float* __restrict__ g,
                                                 const float* __restrict__ beta,
                                                 void* __restrict__ outp) {
  const int wv = blockIdx.x * 4 + (threadIdx.x >> 6);
  const int lane = threadIdx.x & 63;
  const size_t idx = (size_t)wv * 64 + lane;
  ushort4 u = in[idx];
  float x0 = bf2f(u.x), x1 = bf2f(u.y), x2 = bf2f(u.z), x3 = bf2f(u.w);
  float sum = x0 + x1 + x2 + x3;
#pragma unroll
  for (int o = 32; o >= 1; o >>= 1) sum += __shfl_xor(sum, o, 64);
  const float mu = sum * (1.f / 256.f);
  float d0 = x0 - mu, d1 = x1 - mu, d2 = x2 - mu, d3 = x3 - mu;
  float ss = d0 * d0 + d1 * d1 + d2 * d2 + d3 * d3;
#pragma unroll
  for (int o = 32; o >= 1; o >>= 1) ss += __shfl_xor(ss, o, 64);
  const float rs = rsqrtf(ss * (1.f / 256.f) + 1e-5f);
  float4 gg = ((const float4*)g)[lane], bb = ((const float4*)beta)[lane];
  float y0 = d0 * rs * gg.x + bb.x;
  float y1 = d1 * rs * gg.y + bb.y;
  float y2 = d2 * rs * gg.z + bb.z;
  float y3 = d3 * rs * gg.w + bb.w;
  if (OUT_F32) ((float4*)outp)[idx] = make_float4(y0, y1, y2, y3);
  else ((ushort4*)outp)[idx] = make_ushort4(f2bf(y0), f2bf(y1), f2bf(y2), f2bf(y3));
}

extern "C" void kernel_launch(void* const* d_in, const int* in_sizes, int n_in,
                              void* d_out, int out_size, void* d_ws, size_t ws_size,
                              hipStream_t stream) {
  (void)in_sizes; (void)n_in; (void)out_size; (void)ws_size;
  const float* src    = (const float*)d_in[0];
  const float* pos    = (const float*)d_in[1];
  const float* refp   = (const float*)d_in[2];
  const float* W_off  = (const float*)d_in[3];
  const float* b_off  = (const float*)d_in[4];
  const float* W_attn = (const float*)d_in[5];
  const float* b_attn = (const float*)d_in[6];
  const float* W_val  = (const float*)d_in[7];
  const float* b_val  = (const float*)d_in[8];
  const float* W_out  = (const float*)d_in[9];
  const float* b_out  = (const float*)d_in[10];
  const float* ln1_g  = (const float*)d_in[11];
  const float* ln1_b  = (const float*)d_in[12];
  const float* W1     = (const float*)d_in[13];
  const float* b1     = (const float*)d_in[14];
  const float* W2     = (const float*)d_in[15];
  const float* b2     = (const float*)d_in[16];
  const float* ln2_g  = (const float*)d_in[17];
  const float* ln2_b  = (const float*)d_in[18];

  char* ws = (char*)d_ws;
  unsigned short* Wt_val = (unsigned short*)ws;          // 65536
  unsigned short* Wt_oa  = Wt_val + 65536;               // 98304
  unsigned short* Wt_out = Wt_oa + 98304;                // 65536
  unsigned short* Wt_1   = Wt_out + 65536;               // 262144
  unsigned short* Wt_2   = Wt_1 + 262144;                // 262144
  float*          b_oa   = (float*)(Wt_2 + 262144);      // 384
  const size_t WPOOL = 2u * 1024 * 1024;

  const size_t SZ_bf = (size_t)TOKS * 256 * 2;           // 22.3 MB
  const size_t SZ_oa = (size_t)TOKS * 384 * 2;           // 33.4 MB

  unsigned short* srcb = (unsigned short*)(ws + WPOOL);
  unsigned short* qb   = (unsigned short*)(ws + WPOOL + SZ_bf);
  unsigned short* valb = (unsigned short*)(ws + WPOOL + 2 * SZ_bf);
  unsigned short* oab  = (unsigned short*)(ws + WPOOL + 3 * SZ_bf);
  unsigned short* h_bf = (unsigned short*)(ws + WPOOL + 3 * SZ_bf + SZ_oa);
  unsigned short* hb   = (unsigned short*)(ws + WPOOL + 3 * SZ_bf + SZ_oa + SZ_bf);
  // aliases (lifetime-disjoint):
  unsigned short* attnoutb = qb;     // deform out; qb dead after proj
  unsigned short* preLN1b  = valb;   // out-gemm out; valb dead after deform
  unsigned short* preLN2b  = valb;   // W2 out; preLN1b dead after LN1

  // 1. prep + weight transposes + bias concat (one launch)
  prewt_kernel<<<13826, 256, 0, stream>>>(src, pos, srcb, qb,
                                          W_val, W_off, W_attn, W_out, W1, W2, b_off, b_attn,
                                          Wt_val, Wt_oa, Wt_out, Wt_1, Wt_2, b_oa);

  // 2. merged projections: value (N=256) + off/attn (N=384)
  proj_kernel<<<dim3(340, 5), 256, 0, stream>>>(srcb, qb, Wt_val, Wt_oa, b_val, b_oa,
                                                valb, oab);

  // 3. deformable attention (8 tokens/block, XCD-swizzled)
  deform_kernel<<<TOKS / 8, 256, 0, stream>>>(valb, oab, refp, attnoutb);

  // 4. out-proj + residual(src) -> preLN1 (bf16); LN1 -> h_bf
  gemm_out_kernel<<<dim3(340, 2), 256, 0, stream>>>(attnoutb, Wt_out, b_out, srcb, preLN1b);
  ln_kernel<0><<<10880, 256, 0, stream>>>((const ushort4*)preLN1b, ln1_g, ln1_b, h_bf);

  // 5. FFN: W1+relu -> hb; W2 + residual(h) -> preLN2 (bf16)
  gemm_ffn1_kernel<<<dim3(340, 8), 256, 0, stream>>>(h_bf, Wt_1, b1, hb);
  gemm_ffn2_kernel<<<dim3(340, 2), 256, 0, stream>>>(hb, Wt_2, b2, h_bf, preLN2b);

  // 6. LN2 -> d_out (f32)
  ln_kernel<1><<<10880, 256, 0, stream>>>((const ushort4*)preLN2b, ln2_g, ln2_b, d_out);
}

// Round 6
// 436.770 us; speedup vs baseline: 1.3085x; 1.0116x over previous
//
#include <hip/hip_runtime.h>

typedef __bf16 bf16x8 __attribute__((ext_vector_type(8)));
typedef float f32x4 __attribute__((ext_vector_type(4)));

static constexpr int TOKS = 43520;   // B * LQ
static constexpr int LQN  = 21760;

__device__ __forceinline__ unsigned short f2bf(float f) {
  union { float f; unsigned u; } v; v.f = f;
  return (unsigned short)((v.u + 0x7fffu + ((v.u >> 16) & 1u)) >> 16);
}
__device__ __forceinline__ float bf2f(unsigned short b) {
  union { unsigned u; float f; } v; v.u = ((unsigned)b) << 16; return v.f;
}

// ---- fused prep + weight transpose + bias concat (one launch)
__global__ __launch_bounds__(256) void prewt_kernel(
    const float* __restrict__ src, const float* __restrict__ pos,
    unsigned short* __restrict__ srcb, unsigned short* __restrict__ qb,
    const float* __restrict__ W_val, const float* __restrict__ W_off,
    const float* __restrict__ W_attn, const float* __restrict__ W_out,
    const float* __restrict__ W1, const float* __restrict__ W2,
    const float* __restrict__ b_off, const float* __restrict__ b_attn,
    unsigned short* __restrict__ Wt_val, unsigned short* __restrict__ Wt_oa,
    unsigned short* __restrict__ Wt_out,
    unsigned short* __restrict__ Wt_1, unsigned short* __restrict__ Wt_2,
    float* __restrict__ b_oa) {
  const int bid = blockIdx.x;
  if (bid < 10880) {
    int i = bid * 256 + threadIdx.x;
    float4 s = ((const float4*)src)[i], p = ((const float4*)pos)[i];
    ((ushort4*)srcb)[i] = make_ushort4(f2bf(s.x), f2bf(s.y), f2bf(s.z), f2bf(s.w));
    ((ushort4*)qb)[i]   = make_ushort4(f2bf(s.x + p.x), f2bf(s.y + p.y),
                                       f2bf(s.z + p.z), f2bf(s.w + p.w));
    return;
  }
  int gid = (bid - 10880) * 256 + threadIdx.x;
  if (gid >= 754048) return;
  if (gid >= 753664) {
    int i = gid - 753664;
    b_oa[i] = (i < 256) ? b_off[i] : b_attn[i - 256];
    return;
  }
  const float* W; unsigned short* Wt; int idx, K, nsh;
  if (gid < 65536)       { W = W_val;  Wt = Wt_val;          idx = gid;          K = 256;  nsh = 8;  }
  else if (gid < 131072) { W = W_off;  Wt = Wt_oa;           idx = gid - 65536;  K = 256;  nsh = 8;  }
  else if (gid < 163840) { W = W_attn; Wt = Wt_oa + 65536;   idx = gid - 131072; K = 256;  nsh = 7;  }
  else if (gid < 229376) { W = W_out;  Wt = Wt_out;          idx = gid - 163840; K = 256;  nsh = 8;  }
  else if (gid < 491520) { W = W1;     Wt = Wt_1;            idx = gid - 229376; K = 256;  nsh = 10; }
  else                   { W = W2;     Wt = Wt_2;            idx = gid - 491520; K = 1024; nsh = 8;  }
  int k = idx >> nsh, n = idx & ((1 << nsh) - 1);
  Wt[n * K + k] = f2bf(W[idx]);
}

// ---- GEMM body: double-buffered LDS, ONE barrier per K-iter, register prefetch.
// As/Bs point to [2][5120] LDS regions. OUTOP: 1=bf16, 2=relu->bf16, 3=+res->bf16
template <int K, int OUTOP>
__device__ __forceinline__ void gemm_body(unsigned short* __restrict__ As,
                                          unsigned short* __restrict__ Bs,
                                          const unsigned short* __restrict__ A,
                                          const unsigned short* __restrict__ Bt,
                                          const float* __restrict__ bias,
                                          const unsigned short* __restrict__ res,
                                          unsigned short* __restrict__ Cp,
                                          int N, int bm, int bn) {
  const int t = threadIdx.x;
  const int wave = t >> 6, lane = t & 63;
  const int wm = (wave & 1) << 6, wn = (wave >> 1) << 6;
  const int lr = lane & 15, lq = lane >> 4;
  const int row0 = t >> 2, cb0 = (t & 3) << 3;
  f32x4 acc[4][4] = {};
  const unsigned short* ga = A  + (size_t)(bm * 128 + row0) * K + cb0;
  const unsigned short* gb = Bt + (size_t)(bn * 128 + row0) * K + cb0;
  const size_t gs = (size_t)64 * K;
  // prologue prefetch (k0 = 0)
  uint4 pa0 = *(const uint4*)ga;
  uint4 pa1 = *(const uint4*)(ga + gs);
  uint4 pb0 = *(const uint4*)gb;
  uint4 pb1 = *(const uint4*)(gb + gs);
  int p = 0;
#pragma unroll 1
  for (int k0 = 0; k0 < K; k0 += 32) {
    unsigned short* Ab = As + p * 5120;
    unsigned short* Bb = Bs + p * 5120;
    *(uint4*)&Ab[row0 * 40 + cb0] = pa0;
    *(uint4*)&Ab[(row0 + 64) * 40 + cb0] = pa1;
    *(uint4*)&Bb[row0 * 40 + cb0] = pb0;
    *(uint4*)&Bb[(row0 + 64) * 40 + cb0] = pb1;
    __syncthreads();                    // single barrier per iter (dbuf makes it safe)
    if (k0 + 32 < K) {                  // next tile's loads fly during this iter's MFMA
      pa0 = *(const uint4*)(ga + k0 + 32);
      pa1 = *(const uint4*)(ga + gs + k0 + 32);
      pb0 = *(const uint4*)(gb + k0 + 32);
      pb1 = *(const uint4*)(gb + gs + k0 + 32);
    }
    bf16x8 af[4], bfr[4];
#pragma unroll
    for (int i = 0; i < 4; i++) af[i] = *(const bf16x8*)&Ab[(wm + i * 16 + lr) * 40 + lq * 8];
#pragma unroll
    for (int j = 0; j < 4; j++) bfr[j] = *(const bf16x8*)&Bb[(wn + j * 16 + lr) * 40 + lq * 8];
#pragma unroll
    for (int i = 0; i < 4; i++)
#pragma unroll
      for (int j = 0; j < 4; j++)
        acc[i][j] = __builtin_amdgcn_mfma_f32_16x16x32_bf16(af[i], bfr[j], acc[i][j], 0, 0, 0);
    p ^= 1;
  }
  // C/D mapping (m89/m91): col = lane&15, row = (lane>>4)*4 + reg
  const int rb = bm * 128 + wm + lq * 4;
  const int cbase = bn * 128 + wn + lr;
#pragma unroll
  for (int j = 0; j < 4; j++) {
    const int col = cbase + j * 16;
    const float bv = bias[col];
#pragma unroll
    for (int i = 0; i < 4; i++) {
#pragma unroll
      for (int r = 0; r < 4; r++) {
        float v = acc[i][j][r] + bv;
        size_t o = (size_t)(rb + i * 16 + r) * N + col;
        if (OUTOP == 1) Cp[o] = f2bf(v);
        else if (OUTOP == 2) Cp[o] = f2bf(fmaxf(v, 0.f));
        else Cp[o] = f2bf(v + bf2f(res[o]));
      }
    }
  }
}

__global__ __launch_bounds__(256) void proj_kernel(
    const unsigned short* __restrict__ srcb, const unsigned short* __restrict__ qb,
    const unsigned short* __restrict__ Wt_val, const unsigned short* __restrict__ Wt_oa,
    const float* __restrict__ b_val, const float* __restrict__ b_oa,
    unsigned short* __restrict__ valb, unsigned short* __restrict__ oab) {
  __shared__ unsigned short As[2 * 5120];
  __shared__ unsigned short Bs[2 * 5120];
  const int bn = blockIdx.y;
  if (bn < 2)
    gemm_body<256, 1>(As, Bs, srcb, Wt_val, b_val, nullptr, valb, 256, blockIdx.x, bn);
  else
    gemm_body<256, 1>(As, Bs, qb, Wt_oa, b_oa, nullptr, oab, 384, blockIdx.x, bn - 2);
}

__global__ __launch_bounds__(256) void gemm_out_kernel(
    const unsigned short* __restrict__ A, const unsigned short* __restrict__ Bt,
    const float* __restrict__ bias, const unsigned short* __restrict__ res,
    unsigned short* __restrict__ C) {
  __shared__ unsigned short As[2 * 5120];
  __shared__ unsigned short Bs[2 * 5120];
  gemm_body<256, 3>(As, Bs, A, Bt, bias, res, C, 256, blockIdx.x, blockIdx.y);
}

__global__ __launch_bounds__(256) void gemm_ffn1_kernel(
    const unsigned short* __restrict__ A, const unsigned short* __restrict__ Bt,
    const float* __restrict__ bias, unsigned short* __restrict__ C) {
  __shared__ unsigned short As[2 * 5120];
  __shared__ unsigned short Bs[2 * 5120];
  gemm_body<256, 2>(As, Bs, A, Bt, bias, nullptr, C, 1024, blockIdx.x, blockIdx.y);
}

__global__ __launch_bounds__(256) void gemm_ffn2_kernel(
    const unsigned short* __restrict__ A, const unsigned short* __restrict__ Bt,
    const float* __restrict__ bias, const unsigned short* __restrict__ res,
    unsigned short* __restrict__ C) {
  __shared__ unsigned short As[2 * 5120];
  __shared__ unsigned short Bs[2 * 5120];
  gemm_body<1024, 3>(As, Bs, A, Bt, bias, res, C, 256, blockIdx.x, blockIdx.y);
}

// ---- bf16x8 (uint4) fused unpack+FMA into fp32 acc
__device__ __forceinline__ void fma8(uint4 v, float w, float* a) {
  const unsigned uu[4] = {v.x, v.y, v.z, v.w};
#pragma unroll
  for (int i = 0; i < 4; i++) {
    union { unsigned u; float f; } lo, hi;
    lo.u = uu[i] << 16;
    hi.u = uu[i] & 0xffff0000u;
    a[2 * i]     += w * lo.f;
    a[2 * i + 1] += w * hi.f;
  }
}

// ---- deformable attention, two-phase; phase 1 spread over ALL 256 threads,
// tables store precomputed BYTE offsets (int4) — shortest possible address chain.
__global__ __launch_bounds__(256) void deform_kernel(const unsigned short* __restrict__ valb,
                                                     const unsigned short* __restrict__ oab,
                                                     const float* __restrict__ refp,
                                                     unsigned short* __restrict__ outb) {
  __shared__ float4 sW[8][8][17];   // 4 corner weights (x attn)
  __shared__ int4   sI[8][8][17];   // 4 corner BYTE offsets (idx*512)
  const int t = threadIdx.x;
  const int bid = blockIdx.x;                     // 5440 blocks
  const int nb = (bid & 7) * 680 + (bid >> 3);    // XCD-contiguous slices
  const int tok0 = nb * 8;

  // ---- phase 1: thread = (g, h, l); softmax redundant x4, each builds 4 entries
  {
    const int g = t >> 5, h = (t >> 2) & 7, l = t & 3;
    const int tok = tok0 + g;
    const unsigned short* lg = oab + (size_t)tok * 384 + 256 + h * 16;
    uint4 lv0 = ((const uint4*)lg)[0];
    uint4 lv1 = ((const uint4*)lg)[1];
    const unsigned lw[8] = {lv0.x, lv0.y, lv0.z, lv0.w, lv1.x, lv1.y, lv1.z, lv1.w};
    float w[16];
#pragma unroll
    for (int i = 0; i < 8; i++) {
      union { unsigned u; float f; } lo, hi;
      lo.u = lw[i] << 16; hi.u = lw[i] & 0xffff0000u;
      w[2 * i] = lo.f; w[2 * i + 1] = hi.f;
    }
    float mx = -1e30f;
#pragma unroll
    for (int i = 0; i < 16; i++) mx = fmaxf(mx, w[i]);
    float s = 0.f;
#pragma unroll
    for (int i = 0; i < 16; i++) { w[i] = __expf(w[i] - mx); s += w[i]; }
    const float inv = 1.f / s;
    // this level's 8 offset values = one 16B load
    uint4 ov = *(const uint4*)(oab + (size_t)tok * 384 + h * 32 + l * 8);
    const unsigned owv[4] = {ov.x, ov.y, ov.z, ov.w};
    float off[8];
#pragma unroll
    for (int i = 0; i < 4; i++) {
      union { unsigned u; float f; } lo, hi;
      lo.u = owv[i] << 16; hi.u = owv[i] & 0xffff0000u;
      off[2 * i] = lo.f; off[2 * i + 1] = hi.f;
    }
    const float* rp = refp + (size_t)tok * 8 + l * 2;
    const int S = 128 >> l;
    const float Sf = (float)S;
    const float rx = rp[0] * Sf - 0.5f;
    const float ry = rp[1] * Sf - 0.5f;
#pragma unroll
    for (int p = 0; p < 4; p++) {
      const int idx = l * 4 + p;
      const float x = rx + off[p * 2 + 0];
      const float y = ry + off[p * 2 + 1];
      const float aw = w[idx] * inv;
      const float x0f = floorf(x), y0f = floorf(y);
      const int x0 = (int)x0f, y0 = (int)y0f;
      const float fx = x - x0f, fy = y - y0f;
      const bool xin0 = (x0 >= 0) & (x0 < S), xin1 = (x0 + 1 >= 0) & (x0 + 1 < S);
      const bool yin0 = (y0 >= 0) & (y0 < S), yin1 = (y0 + 1 >= 0) & (y0 + 1 < S);
      const int xc0 = min(max(x0, 0), S - 1), xc1 = min(max(x0 + 1, 0), S - 1);
      const int yc0 = min(max(y0, 0), S - 1), yc1 = min(max(y0 + 1, 0), S - 1);
      sW[g][h][idx] = make_float4(aw * (1.f - fx) * (1.f - fy) * (float)(xin0 & yin0),
                                  aw * fx * (1.f - fy)         * (float)(xin1 & yin0),
                                  aw * (1.f - fx) * fy         * (float)(xin0 & yin1),
                                  aw * fx * fy                 * (float)(xin1 & yin1));
      sI[g][h][idx] = make_int4((yc0 * S + xc0) << 9, (yc0 * S + xc1) << 9,
                                (yc1 * S + xc0) << 9, (yc1 * S + xc1) << 9);
    }
  }
  __syncthreads();

  // ---- phase 2: thread = (g, h, dc); 16B loads, byte-offset addressing
  const int g = t >> 5, h = (t >> 2) & 7, dc = t & 3;
  const int tok = tok0 + g;
  const int b = tok / LQN;
  float acc[8] = {0.f, 0.f, 0.f, 0.f, 0.f, 0.f, 0.f, 0.f};
  const int ST[4] = {0, 16384, 20480, 21504};
#pragma unroll
  for (int l = 0; l < 4; l++) {
    const char* vbc = (const char*)(valb + ((size_t)(b * LQN + ST[l])) * 256 + h * 32 + dc * 8);
#pragma unroll
    for (int p = 0; p < 4; p++) {
      float4 W4 = sW[g][h][l * 4 + p];
      int4   I4 = sI[g][h][l * 4 + p];
      uint4 v00 = *(const uint4*)(vbc + I4.x);
      uint4 v10 = *(const uint4*)(vbc + I4.y);
      uint4 v01 = *(const uint4*)(vbc + I4.z);
      uint4 v11 = *(const uint4*)(vbc + I4.w);
      fma8(v00, W4.x, acc);
      fma8(v10, W4.y, acc);
      fma8(v01, W4.z, acc);
      fma8(v11, W4.w, acc);
    }
  }
  unsigned o[4];
#pragma unroll
  for (int i = 0; i < 4; i++)
    o[i] = (unsigned)f2bf(acc[2 * i]) | ((unsigned)f2bf(acc[2 * i + 1]) << 16);
  *(uint4*)(outb + (size_t)tok * 256 + h * 32 + dc * 8) = make_uint4(o[0], o[1], o[2], o[3]);
}

// ---- layernorm on bf16 pre-LN input; one wave per token (64 lanes x 4 elems)
template <int OUT_F32>
__global__ __launch_bounds__(256) void ln_kernel(const ushort4* __restrict__ in,
                                                 const float* __restrict__ g,
                                                 const float* __restrict__ beta,
                                                 void* __restrict__ outp) {
  const int wv = blockIdx.x * 4 + (threadIdx.x >> 6);
  const int lane = threadIdx.x & 63;
  const size_t idx = (size_t)wv * 64 + lane;
  ushort4 u = in[idx];
  float x0 = bf2f(u.x), x1 = bf2f(u.y), x2 = bf2f(u.z), x3 = bf2f(u.w);
  float sum = x0 + x1 + x2 + x3;
#pragma unroll
  for (int o = 32; o >= 1; o >>= 1) sum += __shfl_xor(sum, o, 64);
  const float mu = sum * (1.f / 256.f);
  float d0 = x0 - mu, d1 = x1 - mu, d2 = x2 - mu, d3 = x3 - mu;
  float ss = d0 * d0 + d1 * d1 + d2 * d2 + d3 * d3;
#pragma unroll
  for (int o = 32; o >= 1; o >>= 1) ss += __shfl_xor(ss, o, 64);
  const float rs = rsqrtf(ss * (1.f / 256.f) + 1e-5f);
  float4 gg = ((const float4*)g)[lane], bb = ((const float4*)beta)[lane];
  float y0 = d0 * rs * gg.x + bb.x;
  float y1 = d1 * rs * gg.y + bb.y;
  float y2 = d2 * rs * gg.z + bb.z;
  float y3 = d3 * rs * gg.w + bb.w;
  if (OUT_F32) ((float4*)outp)[idx] = make_float4(y0, y1, y2, y3);
  else ((ushort4*)outp)[idx] = make_ushort4(f2bf(y0), f2bf(y1), f2bf(y2), f2bf(y3));
}

extern "C" void kernel_launch(void* const* d_in, const int* in_sizes, int n_in,
                              void* d_out, int out_size, void* d_ws, size_t ws_size,
                              hipStream_t stream) {
  (void)in_sizes; (void)n_in; (void)out_size; (void)ws_size;
  const float* src    = (const float*)d_in[0];
  const float* pos    = (const float*)d_in[1];
  const float* refp   = (const float*)d_in[2];
  const float* W_off  = (const float*)d_in[3];
  const float* b_off  = (const float*)d_in[4];
  const float* W_attn = (const float*)d_in[5];
  const float* b_attn = (const float*)d_in[6];
  const float* W_val  = (const float*)d_in[7];
  const float* b_val  = (const float*)d_in[8];
  const float* W_out  = (const float*)d_in[9];
  const float* b_out  = (const float*)d_in[10];
  const float* ln1_g  = (const float*)d_in[11];
  const float* ln1_b  = (const float*)d_in[12];
  const float* W1     = (const float*)d_in[13];
  const float* b1     = (const float*)d_in[14];
  const float* W2     = (const float*)d_in[15];
  const float* b2     = (const float*)d_in[16];
  const float* ln2_g  = (const float*)d_in[17];
  const float* ln2_b  = (const float*)d_in[18];

  char* ws = (char*)d_ws;
  unsigned short* Wt_val = (unsigned short*)ws;          // 65536
  unsigned short* Wt_oa  = Wt_val + 65536;               // 98304
  unsigned short* Wt_out = Wt_oa + 98304;                // 65536
  unsigned short* Wt_1   = Wt_out + 65536;               // 262144
  unsigned short* Wt_2   = Wt_1 + 262144;                // 262144
  float*          b_oa   = (float*)(Wt_2 + 262144);      // 384
  const size_t WPOOL = 2u * 1024 * 1024;

  const size_t SZ_bf = (size_t)TOKS * 256 * 2;           // 22.3 MB
  const size_t SZ_oa = (size_t)TOKS * 384 * 2;           // 33.4 MB

  unsigned short* srcb = (unsigned short*)(ws + WPOOL);
  unsigned short* qb   = (unsigned short*)(ws + WPOOL + SZ_bf);
  unsigned short* valb = (unsigned short*)(ws + WPOOL + 2 * SZ_bf);
  unsigned short* oab  = (unsigned short*)(ws + WPOOL + 3 * SZ_bf);
  unsigned short* h_bf = (unsigned short*)(ws + WPOOL + 3 * SZ_bf + SZ_oa);
  unsigned short* hb   = (unsigned short*)(ws + WPOOL + 3 * SZ_bf + SZ_oa + SZ_bf);
  // aliases (lifetime-disjoint):
  unsigned short* attnoutb = qb;     // deform out; qb dead after proj
  unsigned short* preLN1b  = valb;   // out-gemm out; valb dead after deform
  unsigned short* preLN2b  = valb;   // W2 out; preLN1b dead after LN1

  // 1. prep + weight transposes + bias concat (one launch)
  prewt_kernel<<<13826, 256, 0, stream>>>(src, pos, srcb, qb,
                                          W_val, W_off, W_attn, W_out, W1, W2, b_off, b_attn,
                                          Wt_val, Wt_oa, Wt_out, Wt_1, Wt_2, b_oa);

  // 2. merged projections: value (N=256) + off/attn (N=384)
  proj_kernel<<<dim3(340, 5), 256, 0, stream>>>(srcb, qb, Wt_val, Wt_oa, b_val, b_oa,
                                                valb, oab);

  // 3. deformable attention (8 tokens/block, XCD-swizzled)
  deform_kernel<<<TOKS / 8, 256, 0, stream>>>(valb, oab, refp, attnoutb);

  // 4. out-proj + residual(src) -> preLN1 (bf16); LN1 -> h_bf
  gemm_out_kernel<<<dim3(340, 2), 256, 0, stream>>>(attnoutb, Wt_out, b_out, srcb, preLN1b);
  ln_kernel<0><<<10880, 256, 0, stream>>>((const ushort4*)preLN1b, ln1_g, ln1_b, h_bf);

  // 5. FFN: W1+relu -> hb; W2 + residual(h) -> preLN2 (bf16)
  gemm_ffn1_kernel<<<dim3(340, 8), 256, 0, stream>>>(h_bf, Wt_1, b1, hb);
  gemm_ffn2_kernel<<<dim3(340, 2), 256, 0, stream>>>(hb, Wt_2, b2, h_bf, preLN2b);

  // 6. LN2 -> d_out (f32)
  ln_kernel<1><<<10880, 256, 0, stream>>>((const ushort4*)preLN2b, ln2_g, ln2_b, d_out);
}